// Round 1
// baseline (141.657 us; speedup 1.0000x reference)
//
#include <hip/hip_runtime.h>

// NonImagingRod: per-ray damped-Newton (LM) root find on f(t) = A t^2 + B t + C.
// Round-10: packed-FP32 math. Counters showed 43-44us invariant to occupancy
// (R8: 8 blocks/CU == R9: 4 blocks/CU) with VALUBusy ~47% -> SIMD issue port /
// chain-latency bound, not waves, not memory (FETCH 49MB, hbm 14%).
// CDNA4 has full-rate packed fp32 (v_pk_fma_f32 / v_pk_mul_f32): pack the 4
// concurrently-iterated rays into 2 float2 lanes -> fast-VALU instrs per
// iteration halve (24 -> 12 per 4 rays). rcp stays scalar (no packed trans).
// Per-element arithmetic is bit-identical fp32 -> absmax must stay 0.0.
// Grid shape: back to R8's proven 2-chunk pipeline, 2048 blocks = 8 blocks/CU.
//
// Codegen notes (hard-won):
//  - 8 SIMULTANEOUSLY-iterated rays (R2-5): spill wall. 4 iterated rays +
//    24 prefetch regs is the proven-clean shape (R8: VGPR 32, FETCH stable).
//  - No-spill signature: FETCH_SIZE stable ~49-50 MB.
//  - Clamp(+-1000) provably inactive; rcp ~1ulp fine (absmax 0.0, R2-R9).
//  - Watch VGPR_Count <= 64 (keeps 8 waves/SIMD possible); pk ops need
//    even-aligned pairs, expect modest rise from 40.

#define LM_ITERS 31
constexpr float DAMPING = 0.5f;

typedef float v2f __attribute__((ext_vector_type(2)));

__global__ __launch_bounds__(256) void rod_kernel(
    const float* __restrict__ P, const float* __restrict__ V,
    const float* __restrict__ Rm, const float* __restrict__ Tv,
    const float* __restrict__ c_ptr, double* __restrict__ ws, int n)
{
    const float c  = c_ptr[0];
    const float r00 = Rm[0], r01 = Rm[1], r02 = Rm[2];
    const float r10 = Rm[3], r11 = Rm[4], r12 = Rm[5];
    const float r20 = Rm[6], r21 = Rm[7], r22 = Rm[8];
    const float t0 = Tv[0], t1 = Tv[1], t2 = Tv[2];

    const int tid      = blockIdx.x * blockDim.x + threadIdx.x;
    const int nthreads = gridDim.x * blockDim.x;

    const float4* P4 = (const float4*)P;
    const float4* V4 = (const float4*)V;

    double acc = 0.0;

    // State for 4 rays packed as 2 float2 pairs (v_pk_* operands).
    v2f nA2[2], f2[2], fp2[2];

    auto setup4 = [&](const float4& qa, const float4& qb, const float4& qc,
                      const float4& ua, const float4& ub, const float4& uc) {
        const float px[4] = {qa.x, qa.w, qb.z, qc.y};
        const float py[4] = {qa.y, qb.x, qb.w, qc.z};
        const float pz[4] = {qa.z, qb.y, qc.x, qc.w};
        const float wx[4] = {ua.x, ua.w, ub.z, uc.y};
        const float wy[4] = {ua.y, ub.x, ub.w, uc.z};
        const float wz[4] = {ua.z, ub.y, uc.x, uc.w};
        float nA[4], f0[4], fp0[4];
        #pragma unroll
        for (int r = 0; r < 4; ++r) {
            const float qx = px[r] - t0, qy = py[r] - t1, qz = pz[r] - t2;
            const float plx = qx * r00 + qy * r10 + qz * r20;
            const float ply = qx * r01 + qy * r11 + qz * r21;
            const float plz = qx * r02 + qy * r12 + qz * r22;
            const float vlx = wx[r] * r00 + wy[r] * r10 + wz[r] * r20;
            const float vly = wx[r] * r01 + wy[r] * r11 + wz[r] * r21;
            const float vlz = wx[r] * r02 + wy[r] * r12 + wz[r] * r22;
            nA[r]  = c * (vly * vly + vlz * vlz);                 // -A
            f0[r]  = plx - c * (ply * ply + plz * plz);           // f(0)  = C
            fp0[r] = vlx - 2.0f * c * (ply * vly + plz * vlz);    // f'(0) = B
        }
        nA2[0] = (v2f){nA[0], nA[1]};  nA2[1] = (v2f){nA[2], nA[3]};
        f2[0]  = (v2f){f0[0], f0[1]};  f2[1]  = (v2f){f0[2], f0[3]};
        fp2[0] = (v2f){fp0[0], fp0[1]}; fp2[1] = (v2f){fp0[2], fp0[3]};
    };

    // delta = f*f'/(f'^2+damping); tmp = f' - A*delta;
    // f <- f - delta*tmp (exact quadratic); f' <- tmp - A*delta.
    // Packed: 6 v_pk ops + 2 scalar rcp per float2 pair.
    const v2f damp = (v2f){DAMPING, DAMPING};
    auto iterate = [&]() {
        #pragma unroll 1
        for (int it = 0; it < LM_ITERS; ++it) {
            #pragma unroll
            for (int p = 0; p < 2; ++p) {
                const v2f den = __builtin_elementwise_fma(fp2[p], fp2[p], damp);
                v2f rcp;
                rcp.x = __builtin_amdgcn_rcpf(den.x);   // ~1 ulp; LM self-corrects
                rcp.y = __builtin_amdgcn_rcpf(den.y);
                const v2f d   = (f2[p] * fp2[p]) * rcp;
                const v2f tmp = __builtin_elementwise_fma(nA2[p], d, fp2[p]);
                f2[p]  = __builtin_elementwise_fma(-d, tmp, f2[p]);
                fp2[p] = __builtin_elementwise_fma(nA2[p], d, tmp);
            }
        }
    };

    auto accum = [&](int g) {
        const float fv[4] = {f2[0].x, f2[0].y, f2[1].x, f2[1].y};
        #pragma unroll
        for (int r = 0; r < 4; ++r)
            if (4 * g + r < n) acc += (double)fv[r] * (double)fv[r];
    };

    const int g0 = tid;
    const int g1 = tid + nthreads;

    // ---- chunk 0 load ----
    float4 a0{}, b0{}, c0{}, u0{}, v0{}, w0{};
    if (4 * g0 < n) {
        a0 = P4[g0 * 3 + 0]; b0 = P4[g0 * 3 + 1]; c0 = P4[g0 * 3 + 2];
        u0 = V4[g0 * 3 + 0]; v0 = V4[g0 * 3 + 1]; w0 = V4[g0 * 3 + 2];
    }
    setup4(a0, b0, c0, u0, v0, w0);

    // ---- prefetch chunk 1, iterate chunk 0 ----
    float4 a1{}, b1{}, c1{}, u1{}, v1{}, w1{};
    if (4 * g1 < n) {
        a1 = P4[g1 * 3 + 0]; b1 = P4[g1 * 3 + 1]; c1 = P4[g1 * 3 + 2];
        u1 = V4[g1 * 3 + 0]; v1 = V4[g1 * 3 + 1]; w1 = V4[g1 * 3 + 2];
    }
    iterate();
    accum(g0);

    // ---- iterate chunk 1 ----
    setup4(a1, b1, c1, u1, v1, w1);
    iterate();
    accum(g1);

    // wave(64) shuffle reduce -> LDS across 4 waves -> one f64 atomic per block
    for (int off = 32; off > 0; off >>= 1)
        acc += __shfl_down(acc, off, 64);
    __shared__ double sacc[4];
    const int lane = threadIdx.x & 63, wave = threadIdx.x >> 6;
    if (lane == 0) sacc[wave] = acc;
    __syncthreads();
    if (threadIdx.x == 0) {
        atomicAdd(ws, sacc[0] + sacc[1] + sacc[2] + sacc[3]);
    }
}

__global__ void rod_finalize(const double* __restrict__ ws,
                             const float* __restrict__ loss_in,
                             float* __restrict__ out, double inv_n)
{
    out[0] = (float)(ws[0] * inv_n + (double)loss_in[0]);
}

extern "C" void kernel_launch(void* const* d_in, const int* in_sizes, int n_in,
                              void* d_out, int out_size, void* d_ws, size_t ws_size,
                              hipStream_t stream) {
    const float* P       = (const float*)d_in[0];
    const float* V       = (const float*)d_in[1];
    const float* R       = (const float*)d_in[2];
    const float* T       = (const float*)d_in[3];
    const float* c       = (const float*)d_in[4];
    const float* loss_in = (const float*)d_in[5];

    const int n = in_sizes[0] / 3;           // number of rays

    // d_ws is poisoned to 0xAA before every launch — zero the accumulator.
    hipMemsetAsync(d_ws, 0, sizeof(double), stream);

    // 8 rays/thread as 2 pipelined 4-ray chunks -> 2048 blocks = 8 blocks/CU
    // (R8's proven shape; with packed math, more waves to hide rcp chains).
    const int threads = (n + 7) / 8;
    const int block   = 256;
    const int grid    = (threads + block - 1) / block;
    rod_kernel<<<grid, block, 0, stream>>>(P, V, R, T, c, (double*)d_ws, n);
    rod_finalize<<<1, 1, 0, stream>>>((const double*)d_ws, loss_in,
                                      (float*)d_out, 1.0 / (double)n);
}

// Round 2
// 140.612 us; speedup vs baseline: 1.0074x; 1.0074x over previous
//
#include <hip/hip_runtime.h>

// NonImagingRod: per-ray damped-Newton (LM) root find on f(t) = A t^2 + B t + C.
// Round-11: double intra-wave ILP. R10 post-mortem: packed fp32 was NEUTRAL
// (42.6us, VALUBusy stuck at 47%) -> issue-COUNT is not the limit. Arithmetic:
// VALU issue floor ~20us (= 47% of the 42.6us wall, matching VALUBusy) with
// the port half-idle despite nominal 8 waves/SIMD -> exposed dependent-chain
// latency (den->rcp->d->tmp->f') with phase-locked waves. Memory aggregate is
// far from binding (50MB fetch ~ 8us at achievable BW).
// Fix: 8 simultaneously-iterated rays per thread (4 packed pairs) = 8
// independent chains -> dependent-use gap ~14-16 cyc within ONE wave, covering
// rcp+fma latency without relying on cross-wave overlap. Single chunk, loads
// upfront (no prefetch pipeline needed; one-time load latency amortizes).
//
// Codegen notes (hard-won):
//  - R2-5's 8-ray spill wall was 8 rays + 24 prefetch regs in flight under a
//    tight reg budget. Single-chunk 8-ray peaks ~60 VGPR (48 transient quads
//    + 24 state). Watch VGPR <= 64 (8 waves/SIMD); spill signature = noisy
//    FETCH_SIZE (stable ~49-50 MB is clean).
//  - Clamp(+-1000) provably inactive; rcp ~1ulp fine (absmax 0.0, R2-R10).
//  - If this round is FLAT ~42us: latency theory dead; next = LDS-coalesced
//    staging of the 48B/thread AoS loads (memory-path theory) or clock check.

#define LM_ITERS 31
constexpr float DAMPING = 0.5f;

typedef float v2f __attribute__((ext_vector_type(2)));

__global__ __launch_bounds__(256) void rod_kernel(
    const float* __restrict__ P, const float* __restrict__ V,
    const float* __restrict__ Rm, const float* __restrict__ Tv,
    const float* __restrict__ c_ptr, double* __restrict__ ws, int n)
{
    const float c  = c_ptr[0];
    const float r00 = Rm[0], r01 = Rm[1], r02 = Rm[2];
    const float r10 = Rm[3], r11 = Rm[4], r12 = Rm[5];
    const float r20 = Rm[6], r21 = Rm[7], r22 = Rm[8];
    const float t0 = Tv[0], t1 = Tv[1], t2 = Tv[2];

    const int tid = blockIdx.x * blockDim.x + threadIdx.x;

    const float4* P4 = (const float4*)P;
    const float4* V4 = (const float4*)V;

    // ---- load 8 rays = 6 float4 from P and 6 from V (upfront, no pipeline)
    float4 pq[6], vq[6];
    #pragma unroll
    for (int j = 0; j < 6; ++j) { pq[j] = float4{0,0,0,0}; vq[j] = float4{0,0,0,0}; }
    if (8 * tid < n) {
        #pragma unroll
        for (int j = 0; j < 6; ++j) {
            pq[j] = P4[tid * 6 + j];
            vq[j] = V4[tid * 6 + j];
        }
    }

    // scatter quads -> 24 floats (fully unrolled, compile-time indices only)
    float pf[24], vf[24];
    #pragma unroll
    for (int j = 0; j < 6; ++j) {
        pf[4*j+0] = pq[j].x; pf[4*j+1] = pq[j].y; pf[4*j+2] = pq[j].z; pf[4*j+3] = pq[j].w;
        vf[4*j+0] = vq[j].x; vf[4*j+1] = vq[j].y; vf[4*j+2] = vq[j].z; vf[4*j+3] = vq[j].w;
    }

    // ---- per-ray setup: 8 rays -> 4 packed pairs of (nA=-A, f=C, fp=B)
    v2f nA2[4], f2[4], fp2[4];
    {
        float nA[8], f0[8], fp0[8];
        #pragma unroll
        for (int r = 0; r < 8; ++r) {
            const float qx = pf[3*r+0] - t0, qy = pf[3*r+1] - t1, qz = pf[3*r+2] - t2;
            const float wx = vf[3*r+0],      wy = vf[3*r+1],      wz = vf[3*r+2];
            const float plx = qx * r00 + qy * r10 + qz * r20;
            const float ply = qx * r01 + qy * r11 + qz * r21;
            const float plz = qx * r02 + qy * r12 + qz * r22;
            const float vlx = wx * r00 + wy * r10 + wz * r20;
            const float vly = wx * r01 + wy * r11 + wz * r21;
            const float vlz = wx * r02 + wy * r12 + wz * r22;
            nA[r]  = c * (vly * vly + vlz * vlz);                 // -A
            f0[r]  = plx - c * (ply * ply + plz * plz);           // f(0)  = C
            fp0[r] = vlx - 2.0f * c * (ply * vly + plz * vlz);    // f'(0) = B
        }
        #pragma unroll
        for (int p = 0; p < 4; ++p) {
            nA2[p] = (v2f){nA[2*p], nA[2*p+1]};
            f2[p]  = (v2f){f0[2*p], f0[2*p+1]};
            fp2[p] = (v2f){fp0[2*p], fp0[2*p+1]};
        }
    }

    // delta = f*f'/(f'^2+damping); tmp = f' - A*delta;
    // f <- f - delta*tmp (exact quadratic); f' <- tmp - A*delta.
    // 8 independent chains (4 pairs) per iteration -> latency self-hiding.
    const v2f damp = (v2f){DAMPING, DAMPING};
    #pragma unroll 1
    for (int it = 0; it < LM_ITERS; ++it) {
        #pragma unroll
        for (int p = 0; p < 4; ++p) {
            const v2f den = __builtin_elementwise_fma(fp2[p], fp2[p], damp);
            v2f rcp;
            rcp.x = __builtin_amdgcn_rcpf(den.x);   // ~1 ulp; LM self-corrects
            rcp.y = __builtin_amdgcn_rcpf(den.y);
            const v2f d   = (f2[p] * fp2[p]) * rcp;
            const v2f tmp = __builtin_elementwise_fma(nA2[p], d, fp2[p]);
            f2[p]  = __builtin_elementwise_fma(-d, tmp, f2[p]);
            fp2[p] = __builtin_elementwise_fma(nA2[p], d, tmp);
        }
    }

    // ---- accumulate sum of f^2 over this thread's 8 rays (f64)
    double acc = 0.0;
    {
        const float fv[8] = {f2[0].x, f2[0].y, f2[1].x, f2[1].y,
                             f2[2].x, f2[2].y, f2[3].x, f2[3].y};
        #pragma unroll
        for (int r = 0; r < 8; ++r)
            if (8 * tid + r < n) acc += (double)fv[r] * (double)fv[r];
    }

    // wave(64) shuffle reduce -> LDS across 4 waves -> one f64 atomic per block
    for (int off = 32; off > 0; off >>= 1)
        acc += __shfl_down(acc, off, 64);
    __shared__ double sacc[4];
    const int lane = threadIdx.x & 63, wave = threadIdx.x >> 6;
    if (lane == 0) sacc[wave] = acc;
    __syncthreads();
    if (threadIdx.x == 0) {
        atomicAdd(ws, sacc[0] + sacc[1] + sacc[2] + sacc[3]);
    }
}

__global__ void rod_finalize(const double* __restrict__ ws,
                             const float* __restrict__ loss_in,
                             float* __restrict__ out, double inv_n)
{
    out[0] = (float)(ws[0] * inv_n + (double)loss_in[0]);
}

extern "C" void kernel_launch(void* const* d_in, const int* in_sizes, int n_in,
                              void* d_out, int out_size, void* d_ws, size_t ws_size,
                              hipStream_t stream) {
    const float* P       = (const float*)d_in[0];
    const float* V       = (const float*)d_in[1];
    const float* R       = (const float*)d_in[2];
    const float* T       = (const float*)d_in[3];
    const float* c       = (const float*)d_in[4];
    const float* loss_in = (const float*)d_in[5];

    const int n = in_sizes[0] / 3;           // number of rays

    // d_ws is poisoned to 0xAA before every launch — zero the accumulator.
    hipMemsetAsync(d_ws, 0, sizeof(double), stream);

    // 8 rays/thread, single chunk, all iterated concurrently (4 packed pairs).
    // 2048 blocks = 8 blocks/CU = nominal full co-residency.
    const int threads = (n + 7) / 8;
    const int block   = 256;
    const int grid    = (threads + block - 1) / block;
    rod_kernel<<<grid, block, 0, stream>>>(P, V, R, T, c, (double*)d_ws, n);
    rod_finalize<<<1, 1, 0, stream>>>((const double*)d_ws, loss_in,
                                      (float*)d_out, 1.0 / (double)n);
}